// Round 3
// baseline (186.604 us; speedup 1.0000x reference)
//
#include <hip/hip_runtime.h>

// x: (B, C, D, H, W) float32; out: (B, D, H, W) float32 = log(det(I+grad u))^2.
constexpr int B = 2, C = 3, D = 128, H = 192, W = 192;
constexpr int sH = W;          // stride of h (elements)
constexpr int sD = H * W;      // stride of d
constexpr int sC = D * H * W;  // stride of c
constexpr int sB = C * sC;     // stride of b (fits int32; max index ~28.3M)
constexpr int W4 = W / 4;      // 48 float4-groups per row
constexpr int Dc = 8;          // d-planes marched per thread
constexpr int NCH = D / Dc;    // 16 chunks
constexpr int NT = B * NCH * H * W4;  // 294912 threads = 1152 * 256 exact

// Each thread owns 4 consecutive w-voxels and marches Dc planes along D,
// keeping a rolling 3-plane window of center float4s in registers so the
// D-gradient taps are register reuse instead of loads.
// Per d-step: 3 center float4 (plane d+1) + 6 H-tap float4 + 6 edge scalars.
__global__ __launch_bounds__(256, 4) void jac_logdet_sq(
    const float* __restrict__ x, float* __restrict__ out) {
    const int g = blockIdx.x * 256 + threadIdx.x;
    const int w4 = g % W4;
    const int w0 = w4 * 4;
    int t = g / W4;
    const int h = t % H;
    t /= H;
    const int chunk = t % NCH;
    const int b = t / NCH;
    const int d0 = chunk * Dc;

    const int rowbase = b * sB + h * sH + w0;   // 16B-aligned

    const int offL  = (w0 > 0) ? -1 : 0;        // clamped taps; boundary
    const int offR  = (w0 + 4 < W) ? 4 : 3;     //  one-sidedness comes from
    const int offHp = (h < H - 1) ? sH : 0;     //  the coefficient selects
    const int offHm = (h > 0) ? sH : 0;
    const float chc = (h > 0 && h < H - 1) ? 0.5f : 1.0f;

    // Rolling window: cm = center plane d-1, c0 = center plane d.
    float cm[3][4], c0[3][4];
#pragma unroll
    for (int c = 0; c < 3; ++c) {
        const float* p = x + rowbase + c * sC + d0 * sD;
        const float4 v0 = *(const float4*)p;
        c0[c][0] = v0.x; c0[c][1] = v0.y; c0[c][2] = v0.z; c0[c][3] = v0.w;
        if (d0 > 0) {
            const float4 vm = *(const float4*)(p - sD);
            cm[c][0] = vm.x; cm[c][1] = vm.y; cm[c][2] = vm.z; cm[c][3] = vm.w;
        } else {  // d==0 one-sided: backward tap collapses to center
            cm[c][0] = v0.x; cm[c][1] = v0.y; cm[c][2] = v0.z; cm[c][3] = v0.w;
        }
    }

    int obase = ((b * D + d0) * H + h) * W + w0;

    for (int dd = 0; dd < Dc; ++dd) {
        const int d = d0 + dd;
        const float cdc = (d > 0 && d < D - 1) ? 0.5f : 1.0f;

        float cp[3][4], hp[3][4], hm[3][4], lft[3], rgt[3];
#pragma unroll
        for (int c = 0; c < 3; ++c) {
            const float* p = x + rowbase + c * sC + d * sD;
            if (d < D - 1) {
                const float4 v = *(const float4*)(p + sD);
                cp[c][0] = v.x; cp[c][1] = v.y; cp[c][2] = v.z; cp[c][3] = v.w;
            } else {  // d==D-1 one-sided: forward tap collapses to center
                cp[c][0] = c0[c][0]; cp[c][1] = c0[c][1];
                cp[c][2] = c0[c][2]; cp[c][3] = c0[c][3];
            }
            const float4 vhp = *(const float4*)(p + offHp);
            const float4 vhm = *(const float4*)(p - offHm);
            hp[c][0] = vhp.x; hp[c][1] = vhp.y; hp[c][2] = vhp.z; hp[c][3] = vhp.w;
            hm[c][0] = vhm.x; hm[c][1] = vhm.y; hm[c][2] = vhm.z; hm[c][3] = vhm.w;
            lft[c] = p[offL];
            rgt[c] = p[offR];
        }

        float r[4];
#pragma unroll
        for (int e = 0; e < 4; ++e) {
            float gd[3], gh[3], gw[3];
#pragma unroll
            for (int c = 0; c < 3; ++c) {
                gd[c] = (cp[c][e] - cm[c][e]) * cdc;
                gh[c] = (hp[c][e] - hm[c][e]) * chc;
            }
#pragma unroll
            for (int c = 0; c < 3; ++c) {
                if (e == 0)
                    gw[c] = (w0 == 0) ? (c0[c][1] - c0[c][0])
                                      : 0.5f * (c0[c][1] - lft[c]);
                else if (e == 1) gw[c] = 0.5f * (c0[c][2] - c0[c][0]);
                else if (e == 2) gw[c] = 0.5f * (c0[c][3] - c0[c][1]);
                else
                    gw[c] = (w0 + 4 == W) ? (c0[c][3] - c0[c][2])
                                          : 0.5f * (rgt[c] - c0[c][2]);
            }
            const float a00 = gd[0] + 1.0f, a01 = gd[1], a02 = gd[2];
            const float a10 = gh[0], a11 = gh[1] + 1.0f, a12 = gh[2];
            const float a20 = gw[0], a21 = gw[1], a22 = gw[2] + 1.0f;
            const float det = a00 * (a11 * a22 - a12 * a21)
                            - a01 * (a10 * a22 - a12 * a20)
                            + a02 * (a10 * a21 - a11 * a20);
            const float l = __logf(det);  // det>0; HW log, err ≪ threshold
            r[e] = l * l;
        }

        *(float4*)(out + obase + dd * sD) = make_float4(r[0], r[1], r[2], r[3]);

        // rotate rolling window
#pragma unroll
        for (int c = 0; c < 3; ++c) {
#pragma unroll
            for (int e = 0; e < 4; ++e) {
                cm[c][e] = c0[c][e];
                c0[c][e] = cp[c][e];
            }
        }
    }
}

extern "C" void kernel_launch(void* const* d_in, const int* in_sizes, int n_in,
                              void* d_out, int out_size, void* d_ws, size_t ws_size,
                              hipStream_t stream) {
    const float* x = (const float*)d_in[0];
    float* out = (float*)d_out;
    jac_logdet_sq<<<dim3(NT / 256), dim3(256), 0, stream>>>(x, out);
}

// Round 4
// 185.170 us; speedup vs baseline: 1.0077x; 1.0077x over previous
//
#include <hip/hip_runtime.h>

// x: (B, C, D, H, W) float32; out: (B, D, H, W) float32 = log(det(I+grad u))^2.
constexpr int B = 2, C = 3, D = 128, H = 192, W = 192;
constexpr int sH = W;          // stride of h (elements)
constexpr int sD = H * W;      // stride of d
constexpr int sC = D * H * W;  // stride of c
constexpr int sB = C * sC;     // stride of b (fits int32)
constexpr int W4 = W / 4;      // 48 float4-groups per row
constexpr int NG = B * D * H * W4;  // 2,359,296 groups
constexpr int NB = NG / 256;        // 9216 blocks
constexpr int NXCD = 8;
constexpr int NBX = NB / NXCD;      // 1152 blocks per XCD slab

// R2 structure + XCD-aware swizzle: physical blocks are dispatched
// round-robin across the 8 XCDs (bid % 8). Remap so XCD x processes a
// CONTIGUOUS eighth of the (b,d,h,w4) sweep — then h±/d± tap re-reads hit
// that XCD's own 4 MiB L2 (active window ~1.3 MB) instead of bouncing to
// the shared L3. Tap traffic is ~5x compulsory; serving it from L2
// instead of L3 is the point of this round.
__global__ __launch_bounds__(256) void jac_logdet_sq(
    const float* __restrict__ x, float* __restrict__ out) {
    const int p = blockIdx.x;
    const int bid = (p & (NXCD - 1)) * NBX + (p >> 3);  // xcd-contiguous slab
    const int g = bid * 256 + threadIdx.x;

    const int w4 = g % W4;
    int rid = g / W4;
    const int h = rid % H;
    rid /= H;
    const int d = rid % D;
    const int b = rid / D;
    const int w0 = w4 * 4;

    const int base = b * sB + d * sD + h * sH + w0;  // 16B-aligned

    float gd[3][4], gh[3][4], gw[3][4];

    const int offL = (w0 > 0) ? -1 : 0;          // clamped taps; boundary
    const int offR = (w0 + 4 < W) ? 4 : 3;       //  one-sidedness comes from
    const int offHp = (h < H - 1) ? sH : 0;      //  the coefficient selects
    const int offHm = (h > 0) ? sH : 0;
    const int offDp = (d < D - 1) ? sD : 0;
    const int offDm = (d > 0) ? sD : 0;
    const float ch = (h > 0 && h < H - 1) ? 0.5f : 1.0f;
    const float cd = (d > 0 && d < D - 1) ? 0.5f : 1.0f;

#pragma unroll
    for (int c = 0; c < 3; ++c) {
        const float* p = x + base + c * sC;
        const float4 vm  = *(const float4*)p;
        const float  lft = p[offL];
        const float  rgt = p[offR];
        const float4 vhp = *(const float4*)(p + offHp);
        const float4 vhm = *(const float4*)(p - offHm);
        const float4 vdp = *(const float4*)(p + offDp);
        const float4 vdm = *(const float4*)(p - offDm);

        gh[c][0] = (vhp.x - vhm.x) * ch;
        gh[c][1] = (vhp.y - vhm.y) * ch;
        gh[c][2] = (vhp.z - vhm.z) * ch;
        gh[c][3] = (vhp.w - vhm.w) * ch;

        gd[c][0] = (vdp.x - vdm.x) * cd;
        gd[c][1] = (vdp.y - vdm.y) * cd;
        gd[c][2] = (vdp.z - vdm.z) * cd;
        gd[c][3] = (vdp.w - vdm.w) * cd;

        gw[c][0] = (w0 == 0)     ? (vm.y - vm.x) : 0.5f * (vm.y - lft);
        gw[c][1] = 0.5f * (vm.z - vm.x);
        gw[c][2] = 0.5f * (vm.w - vm.y);
        gw[c][3] = (w0 + 4 == W) ? (vm.w - vm.z) : 0.5f * (rgt - vm.z);
    }

    float r[4];
#pragma unroll
    for (int e = 0; e < 4; ++e) {
        const float a00 = gd[0][e] + 1.0f, a01 = gd[1][e], a02 = gd[2][e];
        const float a10 = gh[0][e], a11 = gh[1][e] + 1.0f, a12 = gh[2][e];
        const float a20 = gw[0][e], a21 = gw[1][e], a22 = gw[2][e] + 1.0f;
        const float det = a00 * (a11 * a22 - a12 * a21)
                        - a01 * (a10 * a22 - a12 * a20)
                        + a02 * (a10 * a21 - a11 * a20);
        const float l = __logf(det);  // det>0; HW log, validated in R3
        r[e] = l * l;
    }

    *(float4*)(out + (long)g * 4) = make_float4(r[0], r[1], r[2], r[3]);
}

extern "C" void kernel_launch(void* const* d_in, const int* in_sizes, int n_in,
                              void* d_out, int out_size, void* d_ws, size_t ws_size,
                              hipStream_t stream) {
    const float* x = (const float*)d_in[0];
    float* out = (float*)d_out;
    jac_logdet_sq<<<dim3(NB), dim3(256), 0, stream>>>(x, out);
}

// Round 5
// 179.558 us; speedup vs baseline: 1.0392x; 1.0313x over previous
//
#include <hip/hip_runtime.h>

// x: (B, C, D, H, W) float32; out: (B, D, H, W) float32 = log(det(I+grad u))^2.
constexpr int B = 2, C = 3, D = 128, H = 192, W = 192;
constexpr int sH = W;          // stride of h (elements)
constexpr int sD = H * W;      // stride of d
constexpr int sC = D * H * W;  // stride of c
constexpr int sB = C * sC;     // stride of b

constexpr int TH = 16;           // tile h-rows
constexpr int TW = 16;           // tile f4-groups (64 floats wide)
constexpr int DC = 4;            // d-planes marched per block
constexpr int HX = H / TH;       // 12 h-tiles
constexpr int WX = (W / 4) / TW; // 3 w-tiles
constexpr int NDC = D / DC;      // 32 d-chunks
constexpr int NB = B * NDC * HX * WX;  // 2304 blocks
constexpr int ROWS = TH + 2;     // 18 staged rows (h-halo)
constexpr int RSTR = TW + 1;     // row stride in f4 (+1 pad vs bank aliasing)
constexpr int CH_STR = ROWS * RSTR;    // 306 f4 per channel
constexpr int BUFSZ = C * CH_STR;      // 918 f4 per buffer (14.7 KB)

// Each thread owns one (h, w4) column of a 16x64 tile and marches DC planes.
// Global traffic ~19.5 B/voxel (vs 12 compulsory): h-taps & w-neighbors come
// from a double-buffered LDS plane stage; d-taps from a rolling 3-plane
// register window. Theory: prior rounds were bound by ~20 B/cy/CU of total
// cache-datapath traffic (~70 B/vox); this cuts requested bytes 3.6x.
__global__ __launch_bounds__(256, 4) void jac_logdet_sq(
    const float* __restrict__ x, float* __restrict__ out) {
    __shared__ float4 lds[2][BUFSZ];

    const int tid = threadIdx.x;
    const int tx = tid & 15;
    const int ty = tid >> 4;

    int bb = blockIdx.x;
    const int wx = bb % WX; bb /= WX;
    const int hx = bb % HX; bb /= HX;
    const int dch = bb % NDC;
    const int b = bb / NDC;

    const int d0 = dch * DC;
    const int h0 = hx * TH;
    const int h = h0 + ty;
    const int w0 = (wx * TW + tx) * 4;

    const float* pb = x + b * sB;
    const int cidx = h * sH + w0;     // (h,w) offset within one (c,d) plane

    // halo staging role (tid < 96): channel hc, top/bottom row hr, col htx
    const int hc = tid / 32;
    const int hr = (tid >> 4) & 1;
    const int htx = tid & 15;
    const int hh = hr ? ((h0 + TH < H) ? h0 + TH : H - 1)
                      : ((h0 > 0) ? h0 - 1 : 0);
    const int hidx = hh * sH + (wx * TW + htx) * 4;
    const int hlds = hc * CH_STR + (hr ? (TH + 1) : 0) * RSTR + htx;

    const float chc = (h > 0 && h < H - 1) ? 0.5f : 1.0f;

    float4 cm[3], c0[3], cp[3];

    // ---- prologue: cm = plane d0-1 (clamped), c0 = plane d0; stage d0 ----
    const int dm = (d0 > 0) ? d0 - 1 : 0;
#pragma unroll
    for (int c = 0; c < 3; ++c) {
        c0[c] = *(const float4*)(pb + c * sC + d0 * sD + cidx);
        cm[c] = *(const float4*)(pb + c * sC + dm * sD + cidx);
    }
#pragma unroll
    for (int c = 0; c < 3; ++c)
        lds[0][c * CH_STR + (ty + 1) * RSTR + tx] = c0[c];
    if (tid < 96)
        lds[0][hlds] = *(const float4*)(pb + hc * sC + d0 * sD + hidx);
    __syncthreads();

    int cur = 0;
    int obase = ((b * D + d0) * H + h) * W + w0;

    for (int dd = 0; dd < DC; ++dd) {
        const int d = d0 + dd;
        const int dp = (d + 1 < D) ? d + 1 : D - 1;  // clamp: last plane
        const float cdc = (d > 0 && d < D - 1) ? 0.5f : 1.0f;

        // issue next-plane loads early (overlap latency with compute below)
#pragma unroll
        for (int c = 0; c < 3; ++c)
            cp[c] = *(const float4*)(pb + c * sC + dp * sD + cidx);
        float4 hv;
        const bool do_stage = (dd < DC - 1);
        if (do_stage && tid < 96)
            hv = *(const float4*)(pb + hc * sC + dp * sD + hidx);

        // w-edge scalars (plane d), tile boundary threads only
        float lg[3], rg[3];
        if (tx == 0 && w0 > 0) {
#pragma unroll
            for (int c = 0; c < 3; ++c) lg[c] = pb[c * sC + d * sD + cidx - 1];
        }
        if (tx == 15 && w0 + 4 < W) {
#pragma unroll
            for (int c = 0; c < 3; ++c) rg[c] = pb[c * sC + d * sD + cidx + 4];
        }

        // ---- compute from LDS (h,w taps) + register window (d taps) ----
        const float4* bufc = lds[cur];
        float gd[3][4], gh[3][4], gw[3][4];
#pragma unroll
        for (int c = 0; c < 3; ++c) {
            const float4 hp = bufc[c * CH_STR + (ty + 2) * RSTR + tx];
            const float4 hm = bufc[c * CH_STR + (ty    ) * RSTR + tx];
            gh[c][0] = (hp.x - hm.x) * chc;
            gh[c][1] = (hp.y - hm.y) * chc;
            gh[c][2] = (hp.z - hm.z) * chc;
            gh[c][3] = (hp.w - hm.w) * chc;

            gd[c][0] = (cp[c].x - cm[c].x) * cdc;
            gd[c][1] = (cp[c].y - cm[c].y) * cdc;
            gd[c][2] = (cp[c].z - cm[c].z) * cdc;
            gd[c][3] = (cp[c].w - cm[c].w) * cdc;

            const float lft = (tx == 0) ? lg[c]
                : bufc[c * CH_STR + (ty + 1) * RSTR + tx - 1].w;
            const float rgt = (tx == 15) ? rg[c]
                : bufc[c * CH_STR + (ty + 1) * RSTR + tx + 1].x;
            gw[c][0] = (w0 == 0)     ? (c0[c].y - c0[c].x)
                                     : 0.5f * (c0[c].y - lft);
            gw[c][1] = 0.5f * (c0[c].z - c0[c].x);
            gw[c][2] = 0.5f * (c0[c].w - c0[c].y);
            gw[c][3] = (w0 + 4 == W) ? (c0[c].w - c0[c].z)
                                     : 0.5f * (rgt - c0[c].z);
        }

        float r[4];
#pragma unroll
        for (int e = 0; e < 4; ++e) {
            const float a00 = gd[0][e] + 1.0f, a01 = gd[1][e], a02 = gd[2][e];
            const float a10 = gh[0][e], a11 = gh[1][e] + 1.0f, a12 = gh[2][e];
            const float a20 = gw[0][e], a21 = gw[1][e], a22 = gw[2][e] + 1.0f;
            const float det = a00 * (a11 * a22 - a12 * a21)
                            - a01 * (a10 * a22 - a12 * a20)
                            + a02 * (a10 * a21 - a11 * a20);
            const float l = __logf(det);  // det>0; HW log, validated R3
            r[e] = l * l;
        }
        *(float4*)(out + obase) = make_float4(r[0], r[1], r[2], r[3]);
        obase += sD;

        // ---- stage plane d+1 into the other buffer (skip on last step) ----
        if (do_stage) {
            const int nxt = cur ^ 1;
#pragma unroll
            for (int c = 0; c < 3; ++c)
                lds[nxt][c * CH_STR + (ty + 1) * RSTR + tx] = cp[c];
            if (tid < 96) lds[nxt][hlds] = hv;
            __syncthreads();
            cur = nxt;
        }

        // rotate rolling d-window
#pragma unroll
        for (int c = 0; c < 3; ++c) { cm[c] = c0[c]; c0[c] = cp[c]; }
    }
}

extern "C" void kernel_launch(void* const* d_in, const int* in_sizes, int n_in,
                              void* d_out, int out_size, void* d_ws, size_t ws_size,
                              hipStream_t stream) {
    const float* x = (const float*)d_in[0];
    float* out = (float*)d_out;
    jac_logdet_sq<<<dim3(NB), dim3(256), 0, stream>>>(x, out);
}